// Round 1
// baseline (6978.462 us; speedup 1.0000x reference)
//
#include <hip/hip_runtime.h>
#include <cmath>

// Problem constants (from reference)
#define BS     256
#define KIN    8000      // HIST_LEN * FEAT
#define HID    1024
#define TSTEPS 100
#define ACTD   32
#define OUTD   64

__device__ __forceinline__ float sigmoidf_(float x) {
    return 1.0f / (1.0f + __expf(-x));
}

__device__ __forceinline__ float tanh_fast(float x) {
    // tanh(x) = (e^{2x}-1)/(e^{2x}+1), clamped to avoid inf/inf
    x = fminf(fmaxf(x, -15.0f), 15.0f);
    float e = __expf(2.0f * x);
    return (e - 1.0f) / (e + 1.0f);
}

// -------- Kernel 1: h0 = relu(x @ W_in + b_in) --------
// x: (256, 8000), W_in: (8000, 1024). Tile 32x32, BK=32, 256 threads,
// each thread computes 4 rows x 1 col.
__global__ __launch_bounds__(256) void k_h0(const float* __restrict__ x,
                                            const float* __restrict__ Win,
                                            const float* __restrict__ b_in,
                                            float* __restrict__ h0) {
    __shared__ float As[32][33];
    __shared__ float Bs[32][33];
    const int tid = threadIdx.x;
    const int tx = tid & 31;        // col within tile
    const int ty = tid >> 5;        // 0..7
    const int n0 = blockIdx.x * 32;
    const int m0 = blockIdx.y * 32;
    float acc[4] = {0.f, 0.f, 0.f, 0.f};

    for (int k0 = 0; k0 < KIN; k0 += 32) {
#pragma unroll
        for (int i = 0; i < 4; i++) {
            int r = ty + 8 * i;
            As[r][tx] = x[(size_t)(m0 + r) * KIN + k0 + tx];
            Bs[r][tx] = Win[(size_t)(k0 + r) * HID + n0 + tx];
        }
        __syncthreads();
#pragma unroll
        for (int kk = 0; kk < 32; kk++) {
            float b = Bs[kk][tx];
#pragma unroll
            for (int i = 0; i < 4; i++)
                acc[i] = fmaf(As[ty * 4 + i][kk], b, acc[i]);
        }
        __syncthreads();
    }
#pragma unroll
    for (int i = 0; i < 4; i++) {
        int r = ty * 4 + i;
        float v = acc[i] + b_in[n0 + tx];
        h0[(size_t)(m0 + r) * HID + n0 + tx] = fmaxf(v, 0.0f);
    }
}

// -------- Kernel 2: one GRU step, fully fused --------
// gh = h_prev @ Wh (3 gates), gi = a_t @ Wi + bi (3 gates), gating, write
// h_next and outs[t]. Tile: 32 batch rows x 32 hidden cols. 256 threads,
// each computes 4 (rows) x 1 (col) x 3 gates.
__global__ __launch_bounds__(256) void k_step(const float* __restrict__ h_prev,
                                              float* __restrict__ h_next,
                                              float* __restrict__ outs_t,
                                              const float* __restrict__ action,
                                              const float* __restrict__ Wi,
                                              const float* __restrict__ bi,
                                              const float* __restrict__ Wh,
                                              const float* __restrict__ bhn,
                                              int t) {
    __shared__ float Hs[32][33];
    __shared__ float Ws[3][32][33];
    const int tid = threadIdx.x;
    const int tx = tid & 31;
    const int ty = tid >> 5;
    const int j0 = blockIdx.x * 32;
    const int b0 = blockIdx.y * 32;

    float acc[3][4] = {};   // gh accumulators (r,z,n) x 4 rows

    for (int k0 = 0; k0 < HID; k0 += 32) {
#pragma unroll
        for (int i = 0; i < 4; i++) {
            int r = ty + 8 * i;
            Hs[r][tx] = h_prev[(size_t)(b0 + r) * HID + k0 + tx];
#pragma unroll
            for (int g = 0; g < 3; g++)
                Ws[g][r][tx] = Wh[(size_t)(k0 + r) * (3 * HID) + g * HID + j0 + tx];
        }
        __syncthreads();
#pragma unroll
        for (int kk = 0; kk < 32; kk++) {
            float h[4];
#pragma unroll
            for (int i = 0; i < 4; i++) h[i] = Hs[ty * 4 + i][kk];
#pragma unroll
            for (int g = 0; g < 3; g++) {
                float w = Ws[g][kk][tx];
#pragma unroll
                for (int i = 0; i < 4; i++)
                    acc[g][i] = fmaf(h[i], w, acc[g][i]);
            }
        }
        __syncthreads();
    }

    // gi = a_t @ Wi  (K = 32), reuse the LDS buffers
    float gacc[3][4] = {};
#pragma unroll
    for (int i = 0; i < 4; i++) {
        int r = ty + 8 * i;
        Hs[r][tx] = action[((size_t)(b0 + r) * TSTEPS + t) * ACTD + tx];
#pragma unroll
        for (int g = 0; g < 3; g++)
            Ws[g][r][tx] = Wi[(size_t)r * (3 * HID) + g * HID + j0 + tx];
    }
    __syncthreads();
#pragma unroll
    for (int kk = 0; kk < 32; kk++) {
        float a[4];
#pragma unroll
        for (int i = 0; i < 4; i++) a[i] = Hs[ty * 4 + i][kk];
#pragma unroll
        for (int g = 0; g < 3; g++) {
            float w = Ws[g][kk][tx];
#pragma unroll
            for (int i = 0; i < 4; i++)
                gacc[g][i] = fmaf(a[i], w, gacc[g][i]);
        }
    }

    const int j = j0 + tx;
    const float bir = bi[j];
    const float biz = bi[HID + j];
    const float bin_ = bi[2 * HID + j];
    const float bh = bhn[j];
#pragma unroll
    for (int i = 0; i < 4; i++) {
        int b = b0 + ty * 4 + i;
        float r = sigmoidf_(gacc[0][i] + bir + acc[0][i]);
        float z = sigmoidf_(gacc[1][i] + biz + acc[1][i]);
        float n = tanh_fast(gacc[2][i] + bin_ + r * (acc[2][i] + bh));
        float hp = h_prev[(size_t)b * HID + j];
        float hnew = (1.0f - z) * n + z * hp;
        h_next[(size_t)b * HID + j] = hnew;
        outs_t[(size_t)b * HID + j] = hnew;
    }
}

// -------- Kernel 3: out = outs @ Wo + bo, with (t,b) -> (b,t) transpose --------
// outs rows are m = t*256 + b (layout [t][b][j]); output index is (b*100+t)*64+o.
// Tile: 16 rows x 64 cols, BK=32. 256 threads, each computes 4 rows x 1 col.
__global__ __launch_bounds__(256) void k_out(const float* __restrict__ outs,
                                             const float* __restrict__ Wo,
                                             const float* __restrict__ bo,
                                             float* __restrict__ out) {
    __shared__ float As[16][33];
    __shared__ float Bs[32][65];
    const int tid = threadIdx.x;
    const int tx = tid & 63;        // col 0..63
    const int ty = tid >> 6;        // 0..3
    const int m0 = blockIdx.x * 16;
    float acc[4] = {0.f, 0.f, 0.f, 0.f};

    for (int k0 = 0; k0 < HID; k0 += 32) {
#pragma unroll
        for (int i = 0; i < 2; i++) {
            int e = tid + i * 256;      // 0..511
            int r = e >> 5, c = e & 31;
            As[r][c] = outs[(size_t)(m0 + r) * HID + k0 + c];
        }
#pragma unroll
        for (int i = 0; i < 8; i++) {
            int e = tid + i * 256;      // 0..2047
            int r = e >> 6, c = e & 63;
            Bs[r][c] = Wo[(size_t)(k0 + r) * OUTD + c];
        }
        __syncthreads();
#pragma unroll
        for (int kk = 0; kk < 32; kk++) {
            float b = Bs[kk][tx];
#pragma unroll
            for (int i = 0; i < 4; i++)
                acc[i] = fmaf(As[ty * 4 + i][kk], b, acc[i]);
        }
        __syncthreads();
    }
#pragma unroll
    for (int i = 0; i < 4; i++) {
        int m = m0 + ty * 4 + i;
        int b = m & 255;
        int t = m >> 8;
        out[((size_t)b * TSTEPS + t) * OUTD + tx] = acc[i] + bo[tx];
    }
}

extern "C" void kernel_launch(void* const* d_in, const int* in_sizes, int n_in,
                              void* d_out, int out_size, void* d_ws, size_t ws_size,
                              hipStream_t stream) {
    const float* history = (const float*)d_in[0];   // (256, 250, 32) -> (256, 8000)
    const float* action  = (const float*)d_in[1];   // (256, 100, 32)
    const float* W_in    = (const float*)d_in[2];   // (8000, 1024)
    const float* b_in    = (const float*)d_in[3];   // (1024,)
    const float* Wi      = (const float*)d_in[4];   // (32, 3072)
    const float* bi      = (const float*)d_in[5];   // (3072,)
    const float* Wh      = (const float*)d_in[6];   // (1024, 3072)
    const float* bhn     = (const float*)d_in[7];   // (1024,)
    const float* Wo      = (const float*)d_in[8];   // (1024, 64)
    const float* bo      = (const float*)d_in[9];   // (64,)
    float* out = (float*)d_out;                     // (256, 100, 64)

    // Workspace layout (floats): h ping-pong (2 x 256*1024) + outs (100*256*1024)
    // Total ~107 MB.
    float* ws = (float*)d_ws;
    float* h0buf = ws;
    float* h1buf = ws + (size_t)BS * HID;
    float* outs  = ws + (size_t)2 * BS * HID;

    k_h0<<<dim3(HID / 32, BS / 32), 256, 0, stream>>>(history, W_in, b_in, h0buf);

    float* hp = h0buf;
    float* hn = h1buf;
    for (int t = 0; t < TSTEPS; t++) {
        k_step<<<dim3(HID / 32, BS / 32), 256, 0, stream>>>(
            hp, hn, outs + (size_t)t * BS * HID, action, Wi, bi, Wh, bhn, t);
        float* tmp = hp; hp = hn; hn = tmp;
    }

    k_out<<<(BS * TSTEPS) / 16, 256, 0, stream>>>(outs, Wo, bo, out);
}

// Round 3
// 3783.236 us; speedup vs baseline: 1.8446x; 1.8446x over previous
//
#include <hip/hip_runtime.h>

#define BS   256
#define KIN  8000
#define HID  1024
#define TST  100
#define ACTD 32
#define OUTD 64
#define KTOT 1056            // 1024 (Wh) + 32 (Wi) concatenated K

typedef __attribute__((ext_vector_type(8))) short bf16x8;
typedef __attribute__((ext_vector_type(4))) float f32x4;
typedef unsigned short u16;
typedef unsigned int   u32;

__device__ __forceinline__ u16 f2bf(float f) {
    u32 u = __float_as_uint(f);
    u = (u + 0x7fffu + ((u >> 16) & 1u)) >> 16;   // RNE
    return (u16)u;
}
__device__ __forceinline__ float bf2f(u16 s) {
    return __uint_as_float(((u32)s) << 16);
}
__device__ __forceinline__ float sigm(float x) { return 1.0f / (1.0f + __expf(-x)); }

// ---------------- P1: WcatT_hi/lo[c][k] = split(Wh[k][c] | Wi[k-1024][c]) ----------------
__global__ __launch_bounds__(256) void k_prep_w(const float* __restrict__ Wh,
                                                const float* __restrict__ Wi,
                                                u16* __restrict__ Whi,
                                                u16* __restrict__ Wlo) {
    __shared__ float T[32][33];
    const int k0 = blockIdx.x * 32;      // 0..1024 step 32 (33 tiles)
    const int c0 = blockIdx.y * 32;      // 0..3040
    const int tid = threadIdx.x;
    {
        int k = tid >> 3, c4 = (tid & 7) * 4;
        int kk = k0 + k;
        const float* src = (kk < HID) ? (Wh + (size_t)kk * 3072 + c0 + c4)
                                      : (Wi + (size_t)(kk - HID) * 3072 + c0 + c4);
        float4 v = *(const float4*)src;
        T[k][c4 + 0] = v.x; T[k][c4 + 1] = v.y; T[k][c4 + 2] = v.z; T[k][c4 + 3] = v.w;
    }
    __syncthreads();
    {
        int c = tid >> 3, k4 = (tid & 7) * 4;
        size_t base = (size_t)(c0 + c) * KTOT + k0 + k4;
#pragma unroll
        for (int j = 0; j < 4; j++) {
            float f = T[k4 + j][c];
            u16 hi = f2bf(f);
            u16 lo = f2bf(f - bf2f(hi));
            Whi[base + j] = hi;
            Wlo[base + j] = lo;
        }
    }
}

// ---------------- P2: WoT[n][k] = bf16(Wo[k][n]) ----------------
__global__ __launch_bounds__(256) void k_prep_wo(const float* __restrict__ Wo,
                                                 u16* __restrict__ WoT) {
    int idx = blockIdx.x * 256 + threadIdx.x;   // 65536
    int n = idx & 63, k = idx >> 6;
    WoT[(size_t)n * HID + k] = f2bf(Wo[(size_t)k * OUTD + n]);
}

// ---------------- h0 partial GEMM (fp32, split-K) ----------------
#define H0_SPLIT 10
#define H0_KC    800
__global__ __launch_bounds__(256) void k_h0(const float* __restrict__ x,
                                            const float* __restrict__ Win,
                                            float* __restrict__ part) {
    __shared__ float As[32][33];   // [k][m]
    __shared__ float Bs[32][68];   // [k][n]
    const int n0 = blockIdx.x * 64, m0 = blockIdx.y * 32, s = blockIdx.z;
    const int tid = threadIdx.x;
    const int tm = tid >> 4, tn = tid & 15;   // thread 16x16: 2 rows x 4 cols
    float acc[2][4] = {};

    const int ar = tid >> 3, ac4 = (tid & 7) * 4;
    int br[2], bn4[2];
#pragma unroll
    for (int i = 0; i < 2; i++) { int e = tid + 256 * i; br[i] = e >> 4; bn4[i] = (e & 15) * 4; }
    const int k0 = s * H0_KC;

    float4 aReg = *(const float4*)(x + (size_t)(m0 + ar) * KIN + k0 + ac4);
    float4 bReg0 = *(const float4*)(Win + (size_t)(k0 + br[0]) * HID + n0 + bn4[0]);
    float4 bReg1 = *(const float4*)(Win + (size_t)(k0 + br[1]) * HID + n0 + bn4[1]);

    for (int it = 0; it < 25; it++) {
        __syncthreads();
        As[ac4 + 0][ar] = aReg.x; As[ac4 + 1][ar] = aReg.y;
        As[ac4 + 2][ar] = aReg.z; As[ac4 + 3][ar] = aReg.w;
        *(float4*)&Bs[br[0]][bn4[0]] = bReg0;
        *(float4*)&Bs[br[1]][bn4[1]] = bReg1;
        if (it < 24) {
            int kn = k0 + (it + 1) * 32;
            aReg  = *(const float4*)(x + (size_t)(m0 + ar) * KIN + kn + ac4);
            bReg0 = *(const float4*)(Win + (size_t)(kn + br[0]) * HID + n0 + bn4[0]);
            bReg1 = *(const float4*)(Win + (size_t)(kn + br[1]) * HID + n0 + bn4[1]);
        }
        __syncthreads();
#pragma unroll
        for (int kk = 0; kk < 32; kk++) {
            float a0 = As[kk][tm * 2], a1 = As[kk][tm * 2 + 1];
            float4 b = *(float4*)&Bs[kk][tn * 4];
            acc[0][0] = fmaf(a0, b.x, acc[0][0]); acc[0][1] = fmaf(a0, b.y, acc[0][1]);
            acc[0][2] = fmaf(a0, b.z, acc[0][2]); acc[0][3] = fmaf(a0, b.w, acc[0][3]);
            acc[1][0] = fmaf(a1, b.x, acc[1][0]); acc[1][1] = fmaf(a1, b.y, acc[1][1]);
            acc[1][2] = fmaf(a1, b.z, acc[1][2]); acc[1][3] = fmaf(a1, b.w, acc[1][3]);
        }
    }
    float* dst = part + (size_t)s * (BS * HID);
#pragma unroll
    for (int i = 0; i < 2; i++) {
        float4 v = make_float4(acc[i][0], acc[i][1], acc[i][2], acc[i][3]);
        *(float4*)(dst + (size_t)(m0 + tm * 2 + i) * HID + n0 + tn * 4) = v;
    }
}

__global__ __launch_bounds__(256) void k_h0red(const float* __restrict__ part,
                                               const float* __restrict__ b_in,
                                               float* __restrict__ h0) {
    int idx = (blockIdx.x * 256 + threadIdx.x) * 4;   // 65536 threads x float4
    float4 sv = *(const float4*)(part + idx);
#pragma unroll
    for (int p = 1; p < H0_SPLIT; p++) {
        float4 v = *(const float4*)(part + (size_t)p * (BS * HID) + idx);
        sv.x += v.x; sv.y += v.y; sv.z += v.z; sv.w += v.w;
    }
    int n = idx & (HID - 1);
    float4 b = *(const float4*)(b_in + n);
    sv.x = fmaxf(sv.x + b.x, 0.f); sv.y = fmaxf(sv.y + b.y, 0.f);
    sv.z = fmaxf(sv.z + b.z, 0.f); sv.w = fmaxf(sv.w + b.w, 0.f);
    *(float4*)(h0 + idx) = sv;
}

// ---------------- fused GRU step: MFMA bf16 hi/lo split ----------------
// Tile: 32 batch x 32 j, all 3 gates. Grid (32 j-tiles, 8 b-tiles) = 256 blocks.
// Wave w (of 4) owns 16x16 patch (bi2=w>>1, ji2=w&1) for r,z,n -> in-register gating.
__global__ __launch_bounds__(256) void k_step(const float* __restrict__ h_prev,
                                              const float* __restrict__ action,
                                              const u16* __restrict__ Whi,
                                              const u16* __restrict__ Wlo,
                                              const float* __restrict__ bi,
                                              const float* __restrict__ bhn,
                                              float* __restrict__ h_next,
                                              u16* __restrict__ outs_t,
                                              int t) {
    __shared__ u16 Ah[32][40], Al[32][40];     // 32 b-rows x 32 k (+8 pad; 80B pitch, 16B-aligned)
    __shared__ u16 Bh[96][40], Bl[96][40];     // 96 c-rows (3 gates x 32 j) x 32 k

    const int tid = threadIdx.x;
    const int j0 = blockIdx.x * 32, b0 = blockIdx.y * 32;
    const int w = tid >> 6, lane = tid & 63;
    const int m16 = lane & 15, quad = lane >> 4;
    const int bi2 = w >> 1, ji2 = w & 1;

    f32x4 accR = {0.f, 0.f, 0.f, 0.f};
    f32x4 accZ = {0.f, 0.f, 0.f, 0.f};
    f32x4 accN = {0.f, 0.f, 0.f, 0.f};
    f32x4 accI = {0.f, 0.f, 0.f, 0.f};

    // --- staging maps ---
    const int ar = tid >> 3, ac4 = (tid & 7) * 4;       // A: 32 rows x 8 float4-chunks
    int brow[3], bq[3], bhalf[3];
    const u16* bptr[3];
#pragma unroll
    for (int i = 0; i < 3; i++) {
        int e = tid + 256 * i;            // 0..767
        int hf = (e >= 384) ? 1 : 0;      // 0: hi, 1: lo
        int e2 = e - hf * 384;            // 0..383  (384 is NOT pow2 -- must subtract, not mask!)
        bhalf[i] = hf;
        int r = e2 >> 2;                  // 0..95
        bq[i] = e2 & 3;
        brow[i] = r;
        int c = (r >> 5) * HID + j0 + (r & 31);
        bptr[i] = (hf ? Wlo : Whi) + (size_t)c * KTOT + bq[i] * 8;
    }

    // frag LDS pointers (constant across iters)
    const bf16x8* pAh = (const bf16x8*)&Ah[bi2 * 16 + m16][quad * 8];
    const bf16x8* pAl = (const bf16x8*)&Al[bi2 * 16 + m16][quad * 8];
    const bf16x8* pBh[3]; const bf16x8* pBl[3];
#pragma unroll
    for (int g = 0; g < 3; g++) {
        pBh[g] = (const bf16x8*)&Bh[g * 32 + ji2 * 16 + m16][quad * 8];
        pBl[g] = (const bf16x8*)&Bl[g * 32 + ji2 * 16 + m16][quad * 8];
    }

    // prologue loads (iter 0)
    float4 aReg = *(const float4*)(h_prev + (size_t)(b0 + ar) * HID + ac4);
    int4 bReg[3];
#pragma unroll
    for (int i = 0; i < 3; i++) bReg[i] = *(const int4*)(const void*)(bptr[i]);

    for (int kt = 0; kt < 33; kt++) {
        __syncthreads();
        // store staged A (convert fp32 -> bf16 hi/lo)
        {
            u16 h0_ = f2bf(aReg.x), h1_ = f2bf(aReg.y), h2_ = f2bf(aReg.z), h3_ = f2bf(aReg.w);
            u16 l0_ = f2bf(aReg.x - bf2f(h0_)), l1_ = f2bf(aReg.y - bf2f(h1_));
            u16 l2_ = f2bf(aReg.z - bf2f(h2_)), l3_ = f2bf(aReg.w - bf2f(h3_));
            uint2 ph = make_uint2((u32)h0_ | ((u32)h1_ << 16), (u32)h2_ | ((u32)h3_ << 16));
            uint2 pl = make_uint2((u32)l0_ | ((u32)l1_ << 16), (u32)l2_ | ((u32)l3_ << 16));
            *(uint2*)&Ah[ar][ac4] = ph;
            *(uint2*)&Al[ar][ac4] = pl;
        }
#pragma unroll
        for (int i = 0; i < 3; i++) {
            u16* dst = (bhalf[i] ? &Bl[0][0] : &Bh[0][0]) + brow[i] * 40 + bq[i] * 8;
            *(int4*)(void*)dst = bReg[i];
        }
        // prefetch next iter
        if (kt < 32) {
            int kn = (kt + 1) * 32;
            if (kn < HID)
                aReg = *(const float4*)(h_prev + (size_t)(b0 + ar) * HID + kn + ac4);
            else
                aReg = *(const float4*)(action + (size_t)(b0 + ar) * (TST * ACTD) + t * ACTD + ac4);
#pragma unroll
            for (int i = 0; i < 3; i++) bReg[i] = *(const int4*)(const void*)(bptr[i] + kn);
        }
        __syncthreads();

        bf16x8 ah = *pAh, al = *pAl;
        bf16x8 bhR = *pBh[0], blR = *pBl[0];
        bf16x8 bhZ = *pBh[1], blZ = *pBl[1];
        bf16x8 bhN = *pBh[2], blN = *pBl[2];
        if (kt < 32) {
            accR = __builtin_amdgcn_mfma_f32_16x16x32_bf16(ah, bhR, accR, 0, 0, 0);
            accR = __builtin_amdgcn_mfma_f32_16x16x32_bf16(ah, blR, accR, 0, 0, 0);
            accR = __builtin_amdgcn_mfma_f32_16x16x32_bf16(al, bhR, accR, 0, 0, 0);
            accZ = __builtin_amdgcn_mfma_f32_16x16x32_bf16(ah, bhZ, accZ, 0, 0, 0);
            accZ = __builtin_amdgcn_mfma_f32_16x16x32_bf16(ah, blZ, accZ, 0, 0, 0);
            accZ = __builtin_amdgcn_mfma_f32_16x16x32_bf16(al, bhZ, accZ, 0, 0, 0);
            accN = __builtin_amdgcn_mfma_f32_16x16x32_bf16(ah, bhN, accN, 0, 0, 0);
            accN = __builtin_amdgcn_mfma_f32_16x16x32_bf16(ah, blN, accN, 0, 0, 0);
            accN = __builtin_amdgcn_mfma_f32_16x16x32_bf16(al, bhN, accN, 0, 0, 0);
        } else {
            // action chunk: r,z accumulate; n-gate input term kept separate (accI)
            accR = __builtin_amdgcn_mfma_f32_16x16x32_bf16(ah, bhR, accR, 0, 0, 0);
            accR = __builtin_amdgcn_mfma_f32_16x16x32_bf16(ah, blR, accR, 0, 0, 0);
            accR = __builtin_amdgcn_mfma_f32_16x16x32_bf16(al, bhR, accR, 0, 0, 0);
            accZ = __builtin_amdgcn_mfma_f32_16x16x32_bf16(ah, bhZ, accZ, 0, 0, 0);
            accZ = __builtin_amdgcn_mfma_f32_16x16x32_bf16(ah, blZ, accZ, 0, 0, 0);
            accZ = __builtin_amdgcn_mfma_f32_16x16x32_bf16(al, bhZ, accZ, 0, 0, 0);
            accI = __builtin_amdgcn_mfma_f32_16x16x32_bf16(ah, bhN, accI, 0, 0, 0);
            accI = __builtin_amdgcn_mfma_f32_16x16x32_bf16(ah, blN, accI, 0, 0, 0);
            accI = __builtin_amdgcn_mfma_f32_16x16x32_bf16(al, bhN, accI, 0, 0, 0);
        }
    }

    // epilogue: in-register gating. D element (row=quad*4+rg, col=m16)
    const int j = j0 + ji2 * 16 + m16;
    const float birv = bi[j], bizv = bi[HID + j], binv = bi[2 * HID + j], bhv = bhn[j];
    const int brow0 = b0 + bi2 * 16 + quad * 4;
#pragma unroll
    for (int rg = 0; rg < 4; rg++) {
        int b = brow0 + rg;
        float r = sigm(accR[rg] + birv);
        float z = sigm(accZ[rg] + bizv);
        float n = tanhf(accI[rg] + binv + r * (accN[rg] + bhv));
        float hp = h_prev[(size_t)b * HID + j];
        float hnew = (1.0f - z) * n + z * hp;
        h_next[(size_t)b * HID + j] = hnew;
        outs_t[(size_t)b * HID + j] = f2bf(hnew);
    }
}

// ---------------- k_out: out = outs(bf16) @ Wo + bo, MFMA ----------------
// M=25600 (m = t*256+b), N=64, K=1024. 64x64 tile, wave w: rows w*16.., all 64 n.
__global__ __launch_bounds__(256) void k_out(const u16* __restrict__ outs,
                                             const u16* __restrict__ WoT,
                                             const float* __restrict__ bo,
                                             float* __restrict__ out) {
    __shared__ u16 As[64][40], Bs[64][40];
    const int tid = threadIdx.x;
    const int m0 = blockIdx.x * 64;
    const int w = tid >> 6, lane = tid & 63;
    const int m16 = lane & 15, quad = lane >> 4;
    f32x4 acc[4] = {{0.f,0.f,0.f,0.f},{0.f,0.f,0.f,0.f},{0.f,0.f,0.f,0.f},{0.f,0.f,0.f,0.f}};

    const int ar = tid >> 2, aq = tid & 3;    // 64 rows x 4 16B-chunks
    const u16* aptr = outs + (size_t)(m0 + ar) * HID + aq * 8;
    const u16* bptr = WoT + (size_t)ar * HID + aq * 8;
    int4 aR = *(const int4*)(const void*)aptr;
    int4 bR = *(const int4*)(const void*)bptr;

    for (int kt = 0; kt < 32; kt++) {
        __syncthreads();
        *(int4*)(void*)&As[ar][aq * 8] = aR;
        *(int4*)(void*)&Bs[ar][aq * 8] = bR;
        if (kt < 31) {
            aR = *(const int4*)(const void*)(aptr + (kt + 1) * 32);
            bR = *(const int4*)(const void*)(bptr + (kt + 1) * 32);
        }
        __syncthreads();
        bf16x8 a = *(const bf16x8*)&As[w * 16 + m16][quad * 8];
#pragma unroll
        for (int nt = 0; nt < 4; nt++) {
            bf16x8 b = *(const bf16x8*)&Bs[nt * 16 + m16][quad * 8];
            acc[nt] = __builtin_amdgcn_mfma_f32_16x16x32_bf16(a, b, acc[nt], 0, 0, 0);
        }
    }
    const int mbase = m0 + w * 16 + quad * 4;
#pragma unroll
    for (int nt = 0; nt < 4; nt++) {
        int n = nt * 16 + m16;
        float bov = bo[n];
#pragma unroll
        for (int rg = 0; rg < 4; rg++) {
            int m = mbase + rg;
            int b = m & 255, t = m >> 8;
            out[((size_t)b * TST + t) * OUTD + n] = acc[nt][rg] + bov;
        }
    }
}

extern "C" void kernel_launch(void* const* d_in, const int* in_sizes, int n_in,
                              void* d_out, int out_size, void* d_ws, size_t ws_size,
                              hipStream_t stream) {
    const float* history = (const float*)d_in[0];
    const float* action  = (const float*)d_in[1];
    const float* W_in    = (const float*)d_in[2];
    const float* b_in    = (const float*)d_in[3];
    const float* Wi      = (const float*)d_in[4];
    const float* bi      = (const float*)d_in[5];
    const float* Wh      = (const float*)d_in[6];
    const float* bhn     = (const float*)d_in[7];
    const float* Wo      = (const float*)d_in[8];
    const float* bo      = (const float*)d_in[9];
    float* out = (float*)d_out;

    char* ws = (char*)d_ws;
    float* hbuf0 = (float*)(ws + 0);                    // 1 MB
    float* hbuf1 = (float*)(ws + (1u << 20));           // 1 MB
    u16*   Whi   = (u16*)  (ws + (2u << 20));           // 3072*1056*2 = 6.19 MB
    u16*   Wlo   = (u16*)  (ws + (9u << 20));           // 6.19 MB
    u16*   WoT   = (u16*)  (ws + (16u << 20));          // 128 KB
    float* part  = (float*)(ws + (17u << 20));          // 10 MB
    u16*   outsb = (u16*)  (ws + (28u << 20));          // 50 MB (25600x1024 bf16)

    k_prep_w<<<dim3(33, 96), 256, 0, stream>>>(Wh, Wi, Whi, Wlo);
    k_prep_wo<<<256, 256, 0, stream>>>(Wo, WoT);
    k_h0<<<dim3(16, 8, H0_SPLIT), 256, 0, stream>>>(history, W_in, part);
    k_h0red<<<256, 256, 0, stream>>>(part, b_in, hbuf0);

    float* hp = hbuf0;
    float* hn = hbuf1;
    for (int t = 0; t < TST; t++) {
        k_step<<<dim3(32, 8), 256, 0, stream>>>(hp, action, Whi, Wlo, bi, bhn,
                                                hn, outsb + (size_t)t * BS * HID, t);
        float* tmp = hp; hp = hn; hn = tmp;
    }

    k_out<<<400, 256, 0, stream>>>(outsb, WoT, bo, out);
}

// Round 4
// 1113.531 us; speedup vs baseline: 6.2670x; 3.3975x over previous
//
#include <hip/hip_runtime.h>

#define BS   256
#define KIN  8000
#define HID  1024
#define TST  100
#define ACTD 32
#define OUTD 64
#define KTOT 1056            // 1024 (Wh) + 32 (Wi) concatenated K

typedef __attribute__((ext_vector_type(8))) _Float16 f16x8;
typedef __attribute__((ext_vector_type(4))) float f32x4;
typedef unsigned short u16;
typedef unsigned int   u32;

__device__ __forceinline__ u16 f2h(float f) {
    union { _Float16 h; u16 u; } c;
    c.h = (_Float16)f;             // v_cvt_f16_f32, RNE
    return c.u;
}
__device__ __forceinline__ float sigm(float x) { return 1.0f / (1.0f + __expf(-x)); }

// ---------------- P1: WfT[c][k] = fp16(Wh[k][c] | Wi[k-1024][c]) ----------------
__global__ __launch_bounds__(256) void k_prep_w(const float* __restrict__ Wh,
                                                const float* __restrict__ Wi,
                                                u16* __restrict__ Wf) {
    __shared__ float T[32][33];
    const int k0 = blockIdx.x * 32;      // 33 tiles cover k=0..1055
    const int c0 = blockIdx.y * 32;
    const int tid = threadIdx.x;
    {
        int k = tid >> 3, c4 = (tid & 7) * 4;
        int kk = k0 + k;
        const float* src = (kk < HID) ? (Wh + (size_t)kk * 3072 + c0 + c4)
                                      : (Wi + (size_t)(kk - HID) * 3072 + c0 + c4);
        float4 v = *(const float4*)src;
        T[k][c4 + 0] = v.x; T[k][c4 + 1] = v.y; T[k][c4 + 2] = v.z; T[k][c4 + 3] = v.w;
    }
    __syncthreads();
    {
        int c = tid >> 3, k4 = (tid & 7) * 4;
        size_t base = (size_t)(c0 + c) * KTOT + k0 + k4;
#pragma unroll
        for (int j = 0; j < 4; j++) Wf[base + j] = f2h(T[k4 + j][c]);
    }
}

// ---------------- P2: WoT[n][k] = fp16(Wo[k][n]) ----------------
__global__ __launch_bounds__(256) void k_prep_wo(const float* __restrict__ Wo,
                                                 u16* __restrict__ WoT) {
    int idx = blockIdx.x * 256 + threadIdx.x;   // 65536
    int n = idx & 63, k = idx >> 6;
    WoT[(size_t)n * HID + k] = f2h(Wo[(size_t)k * OUTD + n]);
}

// ---------------- P3: action fp32 -> fp16 (layout preserved) ----------------
__global__ __launch_bounds__(256) void k_prep_act(const float* __restrict__ act,
                                                  u16* __restrict__ acth) {
    int i = (blockIdx.x * 256 + threadIdx.x) * 4;   // 819200 elements, 800 blocks
    float4 v = *(const float4*)(act + i);
    ushort4 h = make_ushort4(f2h(v.x), f2h(v.y), f2h(v.z), f2h(v.w));
    *(ushort4*)(acth + i) = h;
}

// ---------------- h0 partial GEMM (fp32, split-K) ----------------
#define H0_SPLIT 10
#define H0_KC    800
__global__ __launch_bounds__(256) void k_h0(const float* __restrict__ x,
                                            const float* __restrict__ Win,
                                            float* __restrict__ part) {
    __shared__ float As[32][33];   // [k][m]
    __shared__ float Bs[32][68];   // [k][n]
    const int n0 = blockIdx.x * 64, m0 = blockIdx.y * 32, s = blockIdx.z;
    const int tid = threadIdx.x;
    const int tm = tid >> 4, tn = tid & 15;
    float acc[2][4] = {};

    const int ar = tid >> 3, ac4 = (tid & 7) * 4;
    int br[2], bn4[2];
#pragma unroll
    for (int i = 0; i < 2; i++) { int e = tid + 256 * i; br[i] = e >> 4; bn4[i] = (e & 15) * 4; }
    const int k0 = s * H0_KC;

    float4 aReg = *(const float4*)(x + (size_t)(m0 + ar) * KIN + k0 + ac4);
    float4 bReg0 = *(const float4*)(Win + (size_t)(k0 + br[0]) * HID + n0 + bn4[0]);
    float4 bReg1 = *(const float4*)(Win + (size_t)(k0 + br[1]) * HID + n0 + bn4[1]);

    for (int it = 0; it < 25; it++) {
        __syncthreads();
        As[ac4 + 0][ar] = aReg.x; As[ac4 + 1][ar] = aReg.y;
        As[ac4 + 2][ar] = aReg.z; As[ac4 + 3][ar] = aReg.w;
        *(float4*)&Bs[br[0]][bn4[0]] = bReg0;
        *(float4*)&Bs[br[1]][bn4[1]] = bReg1;
        if (it < 24) {
            int kn = k0 + (it + 1) * 32;
            aReg  = *(const float4*)(x + (size_t)(m0 + ar) * KIN + kn + ac4);
            bReg0 = *(const float4*)(Win + (size_t)(kn + br[0]) * HID + n0 + bn4[0]);
            bReg1 = *(const float4*)(Win + (size_t)(kn + br[1]) * HID + n0 + bn4[1]);
        }
        __syncthreads();
#pragma unroll
        for (int kk = 0; kk < 32; kk++) {
            float a0 = As[kk][tm * 2], a1 = As[kk][tm * 2 + 1];
            float4 b = *(float4*)&Bs[kk][tn * 4];
            acc[0][0] = fmaf(a0, b.x, acc[0][0]); acc[0][1] = fmaf(a0, b.y, acc[0][1]);
            acc[0][2] = fmaf(a0, b.z, acc[0][2]); acc[0][3] = fmaf(a0, b.w, acc[0][3]);
            acc[1][0] = fmaf(a1, b.x, acc[1][0]); acc[1][1] = fmaf(a1, b.y, acc[1][1]);
            acc[1][2] = fmaf(a1, b.z, acc[1][2]); acc[1][3] = fmaf(a1, b.w, acc[1][3]);
        }
    }
    float* dst = part + (size_t)s * (BS * HID);
#pragma unroll
    for (int i = 0; i < 2; i++) {
        float4 v = make_float4(acc[i][0], acc[i][1], acc[i][2], acc[i][3]);
        *(float4*)(dst + (size_t)(m0 + tm * 2 + i) * HID + n0 + tn * 4) = v;
    }
}

__global__ __launch_bounds__(256) void k_h0red(const float* __restrict__ part,
                                               const float* __restrict__ b_in,
                                               float* __restrict__ h0,
                                               u16* __restrict__ h0h) {
    int idx = (blockIdx.x * 256 + threadIdx.x) * 4;
    float4 sv = *(const float4*)(part + idx);
#pragma unroll
    for (int p = 1; p < H0_SPLIT; p++) {
        float4 v = *(const float4*)(part + (size_t)p * (BS * HID) + idx);
        sv.x += v.x; sv.y += v.y; sv.z += v.z; sv.w += v.w;
    }
    int n = idx & (HID - 1);
    float4 b = *(const float4*)(b_in + n);
    sv.x = fmaxf(sv.x + b.x, 0.f); sv.y = fmaxf(sv.y + b.y, 0.f);
    sv.z = fmaxf(sv.z + b.z, 0.f); sv.w = fmaxf(sv.w + b.w, 0.f);
    *(float4*)(h0 + idx) = sv;
    *(ushort4*)(h0h + idx) = make_ushort4(f2h(sv.x), f2h(sv.y), f2h(sv.z), f2h(sv.w));
}

// ---------------- fused GRU step: fp16 MFMA, in-block 2-way K-split ----------------
// 512 threads: waves 0-3 (group 0) do k in [0,512); waves 4-7 (group 1) do
// k in [512,1056) incl. the 32-wide action block. Tile 32b x 32j x 3 gates.
// Grid (32 j-tiles, 8 b-tiles) = 256 blocks; j-tile -> XCD = x%8 so the
// 203 KB/j-tile weight slice stays L2-resident across all 100 steps.
__global__ __launch_bounds__(512) void k_step(const u16* __restrict__ aprev,   // fp16 h_{t-1}
                                              const float* __restrict__ hprevf,// fp32 h_{t-1}
                                              const u16* __restrict__ acth,
                                              const u16* __restrict__ Wf,
                                              const float* __restrict__ bi,
                                              const float* __restrict__ bhn,
                                              float* __restrict__ hnextf,
                                              u16* __restrict__ outs_t,
                                              int t) {
    __shared__ u16 A2[2][32][40];       // per-group A tile (pitch 40 u16 = 80B)
    __shared__ u16 B2[2][96][40];       // per-group B tile (3 gates x 32 j)
    __shared__ float RED[4][64][17];    // group-1 accumulators for reduce

    const int tid = threadIdx.x;
    const int g = tid >> 8;             // k-group
    const int tid2 = tid & 255;
    const int lane = tid & 63;
    const int w2 = (tid >> 6) & 3;      // wave within group
    const int m16 = lane & 15, quad = lane >> 4;
    const int bi2 = w2 >> 1, ji2 = w2 & 1;
    const int j0 = blockIdx.x * 32, b0 = blockIdx.y * 32;

    const int niter = g ? 17 : 16;
    const int kbase = g * 512;

    f32x4 accR = {0,0,0,0}, accZ = {0,0,0,0}, accN = {0,0,0,0}, accI = {0,0,0,0};

    // staging maps (per group: A 32x32 halfs = 256 x 8B; B 96x32 halfs = 384 x 16B)
    const int ar = tid2 >> 3, ac = tid2 & 7;
    const u16* aRow = aprev + (size_t)(b0 + ar) * HID;
    const u16* aAct = acth + (size_t)(b0 + ar) * (TST * ACTD) + t * ACTD + ac * 4;
    const int br0 = tid2 >> 2,        bq0 = tid2 & 3;
    const int br1 = (tid2 + 256) >> 2, bq1 = (tid2 + 256) & 3;
    const u16* bp0 = Wf + (size_t)((br0 >> 5) * HID + j0 + (br0 & 31)) * KTOT + kbase + bq0 * 8;
    const u16* bp1 = Wf + (size_t)((br1 >> 5) * HID + j0 + (br1 & 31)) * KTOT + kbase + bq1 * 8;
    const bool b1on = (tid2 < 128);     // wave-uniform

    const f16x8* pA  = (const f16x8*)&A2[g][bi2 * 16 + m16][quad * 8];
    const f16x8* pBr = (const f16x8*)&B2[g][ 0 + ji2 * 16 + m16][quad * 8];
    const f16x8* pBz = (const f16x8*)&B2[g][32 + ji2 * 16 + m16][quad * 8];
    const f16x8* pBn = (const f16x8*)&B2[g][64 + ji2 * 16 + m16][quad * 8];

    // prologue: iter-0 loads
    int2 aReg = *(const int2*)(aRow + kbase + ac * 4);
    int4 bReg0 = *(const int4*)(const void*)bp0;
    int4 bReg1 = b1on ? *(const int4*)(const void*)bp1 : make_int4(0, 0, 0, 0);

    for (int kt = 0; kt < 17; kt++) {
        const bool stage = (kt < niter);
        __syncthreads();
        if (stage) {
            *(int2*)(void*)&A2[g][ar][ac * 4] = aReg;
            *(int4*)(void*)&B2[g][br0][bq0 * 8] = bReg0;
            if (b1on) *(int4*)(void*)&B2[g][br1][bq1 * 8] = bReg1;
        }
        if (kt + 1 < niter) {
            int kk = kbase + (kt + 1) * 32;
            if (g == 1 && kt + 1 == 16)
                aReg = *(const int2*)(aAct);                       // action block
            else
                aReg = *(const int2*)(aRow + kk + ac * 4);
            bReg0 = *(const int4*)(const void*)(bp0 + (kt + 1) * 32);
            if (b1on) bReg1 = *(const int4*)(const void*)(bp1 + (kt + 1) * 32);
        }
        __syncthreads();
        if (stage) {
            f16x8 a  = *pA;
            f16x8 br = *pBr, bz = *pBz, bn = *pBn;
            accR = __builtin_amdgcn_mfma_f32_16x16x32_f16(a, br, accR, 0, 0, 0);
            accZ = __builtin_amdgcn_mfma_f32_16x16x32_f16(a, bz, accZ, 0, 0, 0);
            if (g == 1 && kt == 16)
                accI = __builtin_amdgcn_mfma_f32_16x16x32_f16(a, bn, accI, 0, 0, 0);
            else
                accN = __builtin_amdgcn_mfma_f32_16x16x32_f16(a, bn, accN, 0, 0, 0);
        }
    }

    // cross-group reduce + gate
    if (g == 1) {
#pragma unroll
        for (int i = 0; i < 4; i++) {
            RED[w2][lane][i]      = accR[i];
            RED[w2][lane][4 + i]  = accZ[i];
            RED[w2][lane][8 + i]  = accN[i];
            RED[w2][lane][12 + i] = accI[i];
        }
    }
    __syncthreads();
    if (g == 0) {
        const int j = j0 + ji2 * 16 + m16;
        const float birv = bi[j], bizv = bi[HID + j], binv = bi[2 * HID + j], bhv = bhn[j];
        const int brow0 = b0 + bi2 * 16 + quad * 4;
#pragma unroll
        for (int rg = 0; rg < 4; rg++) {
            int b = brow0 + rg;
            float R = accR[rg] + RED[w2][lane][rg];
            float Z = accZ[rg] + RED[w2][lane][4 + rg];
            float N = accN[rg] + RED[w2][lane][8 + rg];
            float I = RED[w2][lane][12 + rg];
            float r = sigm(R + birv);
            float z = sigm(Z + bizv);
            float n = tanhf(I + binv + r * (N + bhv));
            float hp = hprevf[(size_t)b * HID + j];
            float hnew = (1.0f - z) * n + z * hp;
            hnextf[(size_t)b * HID + j] = hnew;
            outs_t[(size_t)b * HID + j] = f2h(hnew);
        }
    }
}

// ---------------- k_out: out = outs(fp16) @ Wo + bo, MFMA ----------------
__global__ __launch_bounds__(256) void k_out(const u16* __restrict__ outs,
                                             const u16* __restrict__ WoT,
                                             const float* __restrict__ bo,
                                             float* __restrict__ out) {
    __shared__ u16 As[64][40], Bs[64][40];
    const int tid = threadIdx.x;
    const int m0 = blockIdx.x * 64;
    const int w = tid >> 6, lane = tid & 63;
    const int m16 = lane & 15, quad = lane >> 4;
    f32x4 acc[4] = {{0,0,0,0},{0,0,0,0},{0,0,0,0},{0,0,0,0}};

    const int ar = tid >> 2, aq = tid & 3;
    const u16* aptr = outs + (size_t)(m0 + ar) * HID + aq * 8;
    const u16* bptr = WoT + (size_t)ar * HID + aq * 8;
    int4 aR = *(const int4*)(const void*)aptr;
    int4 bR = *(const int4*)(const void*)bptr;

    for (int kt = 0; kt < 32; kt++) {
        __syncthreads();
        *(int4*)(void*)&As[ar][aq * 8] = aR;
        *(int4*)(void*)&Bs[ar][aq * 8] = bR;
        if (kt < 31) {
            aR = *(const int4*)(const void*)(aptr + (kt + 1) * 32);
            bR = *(const int4*)(const void*)(bptr + (kt + 1) * 32);
        }
        __syncthreads();
        f16x8 a = *(const f16x8*)&As[w * 16 + m16][quad * 8];
#pragma unroll
        for (int nt = 0; nt < 4; nt++) {
            f16x8 b = *(const f16x8*)&Bs[nt * 16 + m16][quad * 8];
            acc[nt] = __builtin_amdgcn_mfma_f32_16x16x32_f16(a, b, acc[nt], 0, 0, 0);
        }
    }
    const int mbase = m0 + w * 16 + quad * 4;
#pragma unroll
    for (int nt = 0; nt < 4; nt++) {
        int n = nt * 16 + m16;
        float bov = bo[n];
#pragma unroll
        for (int rg = 0; rg < 4; rg++) {
            int m = mbase + rg;
            int b = m & 255, t = m >> 8;
            out[((size_t)b * TST + t) * OUTD + n] = acc[nt][rg] + bov;
        }
    }
}

extern "C" void kernel_launch(void* const* d_in, const int* in_sizes, int n_in,
                              void* d_out, int out_size, void* d_ws, size_t ws_size,
                              hipStream_t stream) {
    const float* history = (const float*)d_in[0];
    const float* action  = (const float*)d_in[1];
    const float* W_in    = (const float*)d_in[2];
    const float* b_in    = (const float*)d_in[3];
    const float* Wi      = (const float*)d_in[4];
    const float* bi      = (const float*)d_in[5];
    const float* Wh      = (const float*)d_in[6];
    const float* bhn     = (const float*)d_in[7];
    const float* Wo      = (const float*)d_in[8];
    const float* bo      = (const float*)d_in[9];
    float* out = (float*)d_out;

    char* ws = (char*)d_ws;
    float* hbuf0 = (float*)(ws + 0);                    // 1 MB
    float* hbuf1 = (float*)(ws + (1u << 20));           // 1 MB
    u16*   h0h   = (u16*)  (ws + (2u << 20));           // 0.5 MB
    u16*   Wf    = (u16*)  (ws + (3u << 20));           // 6.33 MB
    u16*   WoT   = (u16*)  (ws + (10u << 20));          // 128 KB
    u16*   acth  = (u16*)  (ws + (11u << 20));          // 1.6 MB
    float* part  = (float*)(ws + (13u << 20));          // 10 MB
    u16*   outsb = (u16*)  (ws + (24u << 20));          // 52.4 MB

    k_prep_w<<<dim3(33, 96), 256, 0, stream>>>(Wh, Wi, Wf);
    k_prep_wo<<<256, 256, 0, stream>>>(Wo, WoT);
    k_prep_act<<<800, 256, 0, stream>>>(action, acth);
    k_h0<<<dim3(16, 8, H0_SPLIT), 256, 0, stream>>>(history, W_in, part);
    k_h0red<<<256, 256, 0, stream>>>(part, b_in, hbuf0, h0h);

    float* hp = hbuf0;
    float* hn = hbuf1;
    for (int t = 0; t < TST; t++) {
        const u16* aprev = (t == 0) ? h0h : (outsb + (size_t)(t - 1) * BS * HID);
        k_step<<<dim3(32, 8), 512, 0, stream>>>(aprev, hp, acth, Wf, bi, bhn,
                                                hn, outsb + (size_t)t * BS * HID, t);
        float* tmp = hp; hp = hn; hn = tmp;
    }

    k_out<<<400, 256, 0, stream>>>(outsb, WoT, bo, out);
}